// Round 8
// baseline (95.084 us; speedup 1.0000x reference)
//
#include <hip/hip_runtime.h>

#define N_ATOMS 1024
#define N_EDGES 8192
#define EPAD    (N_EDGES + N_ATOMS)
#define NBATCH  256
#define NEG     0.01f

typedef unsigned int u32;
typedef __attribute__((ext_vector_type(2))) float f32x2;
typedef __attribute__((ext_vector_type(4))) float f32x4;
typedef __attribute__((ext_vector_type(8))) _Float16 f16x8;

__device__ __forceinline__ u32 pkrtz(float lo, float hi) {
    u32 r;
    asm("v_cvt_pkrtz_f16_f32 %0, %1, %2" : "=v"(r) : "v"(lo), "v"(hi));
    return r;
}
#define FMIX_LO(a, w, u) \
    asm("v_fma_mix_f32 %0, %1, %2, %0 op_sel_hi:[0,1,0]" : "+v"(a) : "v"(w), "v"(u))
#define FMIX_HI(a, w, u) \
    asm("v_fma_mix_f32 %0, %1, %2, %0 op_sel:[0,1,0] op_sel_hi:[0,1,0]" : "+v"(a) : "v"(w), "v"(u))

// ---------- workspace layout ----------
#define ROWPTR_OFF 0                       // int[1025]
#define COLW_OFF   4352                    // int2[EPAD] = 73728
#define SELFW_OFF  (4352 + 73728)          // float[1024]
#define PERM_OFF   (SELFW_OFF + 4096)      // int[1024]
#define W2T_OFF    (PERM_OFF + 4096)       // u32[2048] f16-pair W2^T
#define H1_OFF     131072                  // f16[256][1024][64] = 33554432 B (128B rows)
#define POOL_OFF   (H1_OFF + 33554432)     // float[256][64] = 65536 B

// =====================================================================
// Kernel 1: CSR + norm weights + degree-sorted perm + W2^T f16 + pool=0
// =====================================================================
__global__ __launch_bounds__(1024) void build_csr(
    const int* __restrict__ ei,
    int*  __restrict__ rowptr,
    int2* __restrict__ colw,
    float* __restrict__ selfw_g,
    int*  __restrict__ perm_g,
    u32*  __restrict__ w2t,
    const float* __restrict__ W2,
    float* __restrict__ pool)
{
    __shared__ int   sdeg[N_ATOMS];
    __shared__ int   sstart[N_ATOMS];
    __shared__ float sdinv[N_ATOMS];
    __shared__ int   wtot[16];
    __shared__ int   hist[128];
    const int t = threadIdx.x;
    const int lane = t & 63;
    const int w = t >> 6;
    const int* srcA = ei;
    const int* dstA = ei + N_EDGES;

    sdeg[t] = 0;
    if (t < 128) hist[t] = 0;
    #pragma unroll
    for (int i = t; i < NBATCH * 64; i += 1024) pool[i] = 0.0f;
    __syncthreads();
    for (int e = t; e < N_EDGES; e += 1024) atomicAdd(&sdeg[dstA[e]], 1);
    __syncthreads();

    const int deg  = sdeg[t];
    const int pdeg = (deg + 1) & ~1;
    int v = pdeg;
    #pragma unroll
    for (int d = 1; d < 64; d <<= 1) {
        int u = __shfl_up(v, d, 64);
        if (lane >= d) v += u;
    }
    if (lane == 63) wtot[w] = v;
    __syncthreads();
    if (t == 0) {
        int run = 0;
        #pragma unroll
        for (int i = 0; i < 16; ++i) { int c = wtot[i]; wtot[i] = run; run += c; }
    }
    __syncthreads();
    const int start = v - pdeg + wtot[w];
    sstart[t] = start;
    const float dv = rsqrtf((float)deg + 1.0f);
    sdinv[t] = dv;
    rowptr[t] = start;
    if (t == N_ATOMS - 1) rowptr[N_ATOMS] = start + pdeg;
    selfw_g[t] = dv * dv;
    if (deg & 1) colw[start + deg] = make_int2(0, 0);   // zero pad slot

    #pragma unroll
    for (int i = 0; i < 2; ++i) {
        const int idx = t + i * 1024;
        const int c = idx >> 5, kk = idx & 31;
        w2t[c * 32 + kk] = pkrtz(W2[(2 * kk) * 64 + c], W2[(2 * kk + 1) * 64 + c]);
    }

    const int dcl = deg < 127 ? deg : 127;
    atomicAdd(&hist[dcl], 1);
    sdeg[t] = 0;
    __syncthreads();
    if (t == 0) {
        int run = 0;
        for (int i = 0; i < 128; ++i) { int c = hist[i]; hist[i] = run; run += c; }
    }
    __syncthreads();
    const int pos = atomicAdd(&hist[dcl], 1);
    perm_g[pos] = t;
    __syncthreads();

    for (int e = t; e < N_EDGES; e += 1024) {
        const int d = dstA[e];
        const int s = srcA[e];
        const int slot = atomicAdd(&sdeg[d], 1);
        const float wgt = sdinv[s] * sdinv[d];
        colw[sstart[d] + slot] = make_int2(s, __float_as_int(wgt));
    }
}

// =====================================================================
// Kernel 2: h1 = leaky(GEMM1(A'X)) -> global f16 rows. 1 block/molecule.
// =====================================================================
__global__ __launch_bounds__(1024) void k_h1(
    const float* __restrict__ x,
    const int*  __restrict__ rowptr,
    const int2* __restrict__ colw,
    const float* __restrict__ selfw_g,
    const int*  __restrict__ perm_g,
    const float* __restrict__ W1, const float* __restrict__ b1,
    char* __restrict__ h1b)
{
    __shared__ float4 ctile4[N_ATOMS];
    const int t = threadIdx.x;
    const int b = blockIdx.x;
    const float* xb = x + (size_t)b * (3 * N_ATOMS);

    {
        float4 c;
        c.x = xb[3 * t]; c.y = xb[3 * t + 1]; c.z = xb[3 * t + 2]; c.w = 0.0f;
        ctile4[t] = c;
    }
    __syncthreads();

    const int atom = perm_g[t];
    const int s0 = rowptr[atom], s1 = rowptr[atom + 1];
    const float sw = selfw_g[atom];
    const float4 cs = ctile4[atom];
    float A0 = sw * cs.x, A1 = sw * cs.y, A2 = sw * cs.z;
    int4 cur = make_int4(0, 0, 0, 0);
    if (s0 < s1) cur = *(const int4*)(colw + s0);
    for (int j = s0; j < s1; j += 2) {
        const int jn = (j + 2 < s1) ? (j + 2) : s0;
        const int4 nxt = *(const int4*)(colw + jn);
        const float4 c0 = ctile4[cur.x];
        const float4 c1 = ctile4[cur.z];
        const float w0 = __int_as_float(cur.y), w1 = __int_as_float(cur.w);
        A0 += w0 * c0.x + w1 * c1.x;
        A1 += w0 * c0.y + w1 * c1.y;
        A2 += w0 * c0.z + w1 * c1.z;
        cur = nxt;
    }
    u32 pw[32];
    #pragma unroll
    for (int p = 0; p < 32; ++p) {
        f32x2 vv = *(const f32x2*)(b1 + 2 * p);
        vv = __builtin_elementwise_fma((f32x2){A0, A0}, *(const f32x2*)(W1 + 2 * p), vv);
        vv = __builtin_elementwise_fma((f32x2){A1, A1}, *(const f32x2*)(W1 + 64 + 2 * p), vv);
        vv = __builtin_elementwise_fma((f32x2){A2, A2}, *(const f32x2*)(W1 + 128 + 2 * p), vv);
        vv.x = fmaxf(vv.x, NEG * vv.x);
        vv.y = fmaxf(vv.y, NEG * vv.y);
        pw[p] = pkrtz(vv.x, vv.y);
    }
    uint4* row = (uint4*)(h1b + ((size_t)b << 17) + (size_t)atom * 128);
    #pragma unroll
    for (int q = 0; q < 8; ++q)
        row[q] = make_uint4(pw[4 * q], pw[4 * q + 1], pw[4 * q + 2], pw[4 * q + 3]);
}

// =====================================================================
// Kernel 3: gather (L2) + GEMM2 MFMA + leaky + pool atomicAdd.
// 2048 blocks = 256 mol x 8 segs, XCD-grouped (bid%8 == b%8).
// 256 threads: 128 atom-slots x 2 feature-halves (64B each).
// =====================================================================
__global__ __launch_bounds__(256, 5) void k_gather(
    const char* __restrict__ h1b,
    const int*  __restrict__ rowptr,
    const int2* __restrict__ colw,
    const float* __restrict__ selfw_g,
    const int*  __restrict__ perm_g,
    const u32*  __restrict__ w2t, const float* __restrict__ b2,
    float* __restrict__ pool)
{
    __shared__ char stg[128 * 144];
    const int bid = blockIdx.x;
    const int xcd = bid & 7, inner = bid >> 3;
    const int seg = inner & 7, m32 = inner >> 3;
    const int b = xcd + (m32 << 3);
    const char* h1 = h1b + ((size_t)b << 17);

    const int t = threadIdx.x;
    const int slot = t >> 1, half = t & 1;
    const int ho = half * 64;

    const int atom = perm_g[slot * 8 + seg];
    const int r0 = rowptr[atom];
    const int np = (rowptr[atom + 1] - r0) >> 1;
    const float swk = selfw_g[atom];

    float acc[32];
    #pragma unroll
    for (int f = 0; f < 32; ++f) acc[f] = 0.0f;

    // self-loop
    {
        const uint4* own = (const uint4*)(h1 + (size_t)atom * 128 + ho);
        #pragma unroll
        for (int q = 0; q < 4; ++q) {
            const uint4 sv = own[q];
            FMIX_LO(acc[q*8+0], swk, sv.x); FMIX_HI(acc[q*8+1], swk, sv.x);
            FMIX_LO(acc[q*8+2], swk, sv.y); FMIX_HI(acc[q*8+3], swk, sv.y);
            FMIX_LO(acc[q*8+4], swk, sv.z); FMIX_HI(acc[q*8+5], swk, sv.z);
            FMIX_LO(acc[q*8+6], swk, sv.w); FMIX_HI(acc[q*8+7], swk, sv.w);
        }
    }
    // edges (pairs)
    int4 cur = make_int4(0, 0, 0, 0);
    if (np > 0) cur = *(const int4*)(colw + r0);
    for (int j = 0; j < np; ++j) {
        const int4 nxt = (j + 1 < np) ? *(const int4*)(colw + r0 + 2 * (j + 1)) : cur;
        const uint4* rA = (const uint4*)(h1 + (size_t)cur.x * 128 + ho);
        const uint4* rB = (const uint4*)(h1 + (size_t)cur.z * 128 + ho);
        const float wA = __int_as_float(cur.y);
        const float wB = __int_as_float(cur.w);
        #pragma unroll
        for (int q = 0; q < 4; ++q) {
            const uint4 qa = rA[q];
            FMIX_LO(acc[q*8+0], wA, qa.x); FMIX_HI(acc[q*8+1], wA, qa.x);
            FMIX_LO(acc[q*8+2], wA, qa.y); FMIX_HI(acc[q*8+3], wA, qa.y);
            FMIX_LO(acc[q*8+4], wA, qa.z); FMIX_HI(acc[q*8+5], wA, qa.z);
            FMIX_LO(acc[q*8+6], wA, qa.w); FMIX_HI(acc[q*8+7], wA, qa.w);
        }
        #pragma unroll
        for (int q = 0; q < 4; ++q) {
            const uint4 qb = rB[q];
            FMIX_LO(acc[q*8+0], wB, qb.x); FMIX_HI(acc[q*8+1], wB, qb.x);
            FMIX_LO(acc[q*8+2], wB, qb.y); FMIX_HI(acc[q*8+3], wB, qb.y);
            FMIX_LO(acc[q*8+4], wB, qb.z); FMIX_HI(acc[q*8+5], wB, qb.z);
            FMIX_LO(acc[q*8+6], wB, qb.w); FMIX_HI(acc[q*8+7], wB, qb.w);
        }
        cur = nxt;
    }

    // stage to LDS (stride 144 to break frag-read conflicts)
    {
        u32 pk[16];
        #pragma unroll
        for (int i = 0; i < 16; ++i) pk[i] = pkrtz(acc[2 * i], acc[2 * i + 1]);
        uint4* srow = (uint4*)(stg + slot * 144 + ho);
        #pragma unroll
        for (int q = 0; q < 4; ++q)
            srow[q] = make_uint4(pk[4 * q], pk[4 * q + 1], pk[4 * q + 2], pk[4 * q + 3]);
    }
    __syncthreads();

    // GEMM2 MFMA + leaky + pool
    {
        const int w   = t >> 6;
        const int l15 = t & 15;
        const int lq  = (t & 63) >> 4;

        f16x8 wf[2][4];
        #pragma unroll
        for (int kt = 0; kt < 2; ++kt)
            #pragma unroll
            for (int ct = 0; ct < 4; ++ct)
                wf[kt][ct] = *(const f16x8*)(w2t + (ct * 16 + l15) * 32 + kt * 16 + lq * 4);
        float bias[4];
        #pragma unroll
        for (int ct = 0; ct < 4; ++ct) bias[ct] = b2[ct * 16 + l15];

        float pool4[4] = {0.f, 0.f, 0.f, 0.f};
        #pragma unroll
        for (int rt = 0; rt < 2; ++rt) {
            const int row = w * 32 + rt * 16 + l15;
            const char* ab = stg + row * 144 + lq * 16;
            const f16x8 a0 = *(const f16x8*)(ab);
            const f16x8 a1 = *(const f16x8*)(ab + 64);
            #pragma unroll
            for (int ct = 0; ct < 4; ++ct) {
                f32x4 cf = {0.f, 0.f, 0.f, 0.f};
                cf = __builtin_amdgcn_mfma_f32_16x16x32_f16(a0, wf[0][ct], cf, 0, 0, 0);
                cf = __builtin_amdgcn_mfma_f32_16x16x32_f16(a1, wf[1][ct], cf, 0, 0, 0);
                float s = 0.0f;
                #pragma unroll
                for (int r = 0; r < 4; ++r) {
                    const float vv = cf[r] + bias[ct];
                    s += fmaxf(vv, NEG * vv);
                }
                pool4[ct] += s;
            }
        }
        #pragma unroll
        for (int ct = 0; ct < 4; ++ct) {
            pool4[ct] += __shfl_xor(pool4[ct], 16, 64);
            pool4[ct] += __shfl_xor(pool4[ct], 32, 64);
        }
        if ((t & 63) < 16) {
            #pragma unroll
            for (int ct = 0; ct < 4; ++ct)
                atomicAdd(&pool[b * 64 + ct * 16 + l15], pool4[ct]);
        }
    }
}

// =====================================================================
// Kernel 4: mean + project MLP. 256 blocks x 128 threads.
// =====================================================================
__global__ __launch_bounds__(128) void k_proj(
    const float* __restrict__ pool,
    const float* __restrict__ Wp, const float* __restrict__ bp,
    float* __restrict__ out)
{
    const int b = blockIdx.x;
    const int t = threadIdx.x;
    float s = bp[t];
    #pragma unroll
    for (int f = 0; f < 64; ++f)
        s += (pool[b * 64 + f] * (1.0f / 1024.0f)) * Wp[f * 128 + t];
    s = fmaxf(s, NEG * s);
    out[(size_t)b * 128 + t] = s;
}

// =====================================================================
extern "C" void kernel_launch(void* const* d_in, const int* in_sizes, int n_in,
                              void* d_out, int out_size, void* d_ws, size_t ws_size,
                              hipStream_t stream) {
    const float* x  = (const float*)d_in[0];
    const int*   ei = (const int*)  d_in[1];
    const float* W1 = (const float*)d_in[2];
    const float* b1 = (const float*)d_in[3];
    const float* W2 = (const float*)d_in[4];
    const float* b2 = (const float*)d_in[5];
    const float* Wp = (const float*)d_in[6];
    const float* bp = (const float*)d_in[7];
    float* out = (float*)d_out;

    char* ws = (char*)d_ws;
    int*   rowptr = (int*)  (ws + ROWPTR_OFF);
    int2*  colw   = (int2*) (ws + COLW_OFF);
    float* selfw  = (float*)(ws + SELFW_OFF);
    int*   perm   = (int*)  (ws + PERM_OFF);
    u32*   w2t    = (u32*)  (ws + W2T_OFF);
    char*  h1b    = ws + H1_OFF;
    float* pool   = (float*)(ws + POOL_OFF);

    build_csr<<<1, 1024, 0, stream>>>(ei, rowptr, colw, selfw, perm, w2t, W2, pool);
    k_h1<<<NBATCH, 1024, 0, stream>>>(x, rowptr, colw, selfw, perm, W1, b1, h1b);
    k_gather<<<NBATCH * 8, 256, 0, stream>>>(h1b, rowptr, colw, selfw, perm, w2t, b2, pool);
    k_proj<<<NBATCH, 128, 0, stream>>>(pool, Wp, bp, out);
}